// Round 3
// baseline (6086.156 us; speedup 1.0000x reference)
//
#include <hip/hip_runtime.h>

#define SEQ  512
#define IDIM 256
#define HD   1024
#define BT   256
#define NCLS 10

#define GRN 32   // row groups (32 rows of H each)
#define GBN 8    // batch groups (32 batch cols each)
#define NWG (GRN*GBN)
#define TPB 256

typedef __attribute__((ext_vector_type(8))) short short8;
typedef __attribute__((ext_vector_type(4))) float f32x4;
typedef __attribute__((ext_vector_type(4))) unsigned short us4;
typedef __attribute__((ext_vector_type(2))) unsigned long long ull2;

// h double buffer in MFMA-B fragment order (same layout as R1/R2).
// All accesses to g_h / g_flag are system-scope relaxed atomics (sc0+sc1:
// bypass L1 and L2, communicate through the LLC). No wbl2/inv anywhere.
__device__ unsigned short g_h[2][GBN*2*32*64*8];
__device__ float g_hfinal[BT][HD];           // [b][k] fp32 final hidden state
__device__ int g_flag[GBN][128];             // per-WAVE arrival flags (32 WG x 4 waves)
__device__ unsigned int g_done[GBN*64];      // padded done counters

__device__ __forceinline__ unsigned short f2bf(float f){
    unsigned int u = __builtin_bit_cast(unsigned int, f);
    u += 0x7fffu + ((u >> 16) & 1u);         // round-to-nearest-even
    return (unsigned short)(u >> 16);
}

__device__ __forceinline__ float fast_tanh(float v){
    // exact identity: tanh(v) = 1 - 2/(exp(2v)+1); __expf -> v_exp_f32
    float e = __expf(2.0f * v);
    return 1.0f - 2.0f / (e + 1.0f);
}

__device__ __forceinline__ void sys_st64(unsigned short* p, unsigned long long v){
    __hip_atomic_store((unsigned long long*)p, v, __ATOMIC_RELAXED, __HIP_MEMORY_SCOPE_SYSTEM);
}
__device__ __forceinline__ unsigned long long sys_ld64(const unsigned short* p){
    return __hip_atomic_load((const unsigned long long*)p, __ATOMIC_RELAXED, __HIP_MEMORY_SCOPE_SYSTEM);
}

// Arrive (per wave): drain this wave's sc1 h-stores (acked at LLC), then
// publish our flag. Any observer that sees the flag sees our h.
__device__ __forceinline__ void wave_arrive(int gb, int gr, int wv, int l, int val){
    asm volatile("s_waitcnt vmcnt(0)" ::: "memory");
    if (l == 0){
        __hip_atomic_store(&g_flag[gb][gr*4 + wv], val, __ATOMIC_RELAXED, __HIP_MEMORY_SCOPE_SYSTEM);
    }
}

// Wait (per wave, no intra-WG sync): poll all 128 wave-flags of the group.
__device__ __forceinline__ void wave_wait(int gb, int l, int val){
    const int* fl = &g_flag[gb][0];
    int guard = 0;
    for (;;){
        int f0 = __hip_atomic_load(&fl[l],      __ATOMIC_RELAXED, __HIP_MEMORY_SCOPE_SYSTEM);
        int f1 = __hip_atomic_load(&fl[64 + l], __ATOMIC_RELAXED, __HIP_MEMORY_SCOPE_SYSTEM);
        if (__all(f0 >= val && f1 >= val)) break;
        if (++guard > (1 << 20)) break;       // hang safety
    }
    __builtin_amdgcn_fence(__ATOMIC_ACQUIRE, "workgroup"); // compiler barrier; no L2 maint
}

__global__ __launch_bounds__(TPB, 1) void rnn_main(
    const float* __restrict__ x, const float* __restrict__ w_hx,
    const float* __restrict__ w_hh, const float* __restrict__ b_h)
{
    __shared__ unsigned short sAB[2*40*64*8]; // 80 KB frag-order weights

    const int tid = threadIdx.x;
    const int wg  = blockIdx.x;
    const int gr  = wg >> 3;
    const int gb  = wg & 7;   // same-XCD heuristic for group locality (perf only)
    const int r0  = gr * 32;
    const int b0  = gb * 32;
    const int l   = tid & 63;
    const int wv  = tid >> 6;
    const int mt  = wv >> 1;
    const int nt  = wv & 1;

    // ---- W_hh rows [r0,r0+32) -> frag-order LDS, kk = 0..31
    for (int j = 0; j < 32; ++j){
        int idx = j*TPB + tid;
        int r = idx >> 8;
        int k = (idx & 255) << 2;
        f32x4 v = *(const f32x4*)(w_hh + (size_t)(r0 + r)*HD + k);
        int kk  = k >> 5;
        int ln  = (r & 15) | (((k >> 3) & 3) << 4);
        int mtw = r >> 4;
        us4 u = { f2bf(v[0]), f2bf(v[1]), f2bf(v[2]), f2bf(v[3]) };
        *(us4*)&sAB[ ((mtw*40 + kk)*64 + ln)*8 + (k & 7) ] = u;
    }
    // ---- w_hx rows -> frag-order LDS, kk = 32..39
    for (int j = 0; j < 8; ++j){
        int idx = j*TPB + tid;
        int r = idx >> 6;
        int k = (idx & 63) << 2;
        f32x4 v = *(const f32x4*)(w_hx + (size_t)(r0 + r)*IDIM + k);
        int kk  = 32 + (k >> 5);
        int ln  = (r & 15) | (((k >> 3) & 3) << 4);
        int mtw = r >> 4;
        us4 u = { f2bf(v[0]), f2bf(v[1]), f2bf(v[2]), f2bf(v[3]) };
        *(us4*)&sAB[ ((mtw*40 + kk)*64 + ln)*8 + (k & 7) ] = u;
    }
    // ---- zero our kk=gr slice of h buffer 0 (h_init = 0), via sc1 stores
    if (tid < 128){
        int ntz = tid >> 6, lz = tid & 63;
        size_t base = (((size_t)(gb*2 + ntz)*32 + gr)*64 + lz)*8;
        sys_st64(&g_h[0][base],     0ull);
        sys_st64(&g_h[0][base + 4], 0ull);
    }
    f32x4 bh = *(const f32x4*)(b_h + r0 + mt*16 + ((l >> 4) << 2));

    const float* xlane = x + (size_t)(b0 + nt*16 + (l & 15)) * (SEQ*IDIM) + ((l >> 4) << 3);
    const unsigned short* sA = &sAB[ (size_t)mt * 40 * 512 ];
    const size_t hblk = (size_t)(gb*2 + nt) * 32 * 512;

    __syncthreads();                          // weights in LDS + zeros drained
    wave_arrive(gb, gr, wv, l, 1);            // init published

    for (int t = 0; t < SEQ; ++t){
        const int rb = t & 1;
        f32x4 acc = bh;

        // ---- x-part first (independent of h): overlaps producer latency.
        // Plain cached loads: L2 never invalidated now, x stays resident.
        const float* xp = xlane + (size_t)t*IDIM;
        #pragma unroll
        for (int kk = 0; kk < 8; ++kk){
            f32x4 v0 = *(const f32x4*)(xp + kk*32);
            f32x4 v1 = *(const f32x4*)(xp + kk*32 + 4);
            short8 bx;
            bx[0] = (short)f2bf(v0[0]); bx[1] = (short)f2bf(v0[1]);
            bx[2] = (short)f2bf(v0[2]); bx[3] = (short)f2bf(v0[3]);
            bx[4] = (short)f2bf(v1[0]); bx[5] = (short)f2bf(v1[1]);
            bx[6] = (short)f2bf(v1[2]); bx[7] = (short)f2bf(v1[3]);
            short8 a = *(const short8*)&sA[ ((32 + kk)*64 + l)*8 ];
            acc = __builtin_amdgcn_mfma_f32_16x16x32_bf16(a, bx, acc, 0, 0, 0);
        }

        wave_wait(gb, l, t + 1);              // h_t published by all waves of group

        // ---- recurrent part: K = 1024, h read from LLC (sc0+sc1 loads)
        const unsigned short* hbuf = &g_h[rb][hblk];
        #pragma unroll 8
        for (int kk = 0; kk < 32; ++kk){
            short8 a = *(const short8*)&sA[ (kk*64 + l)*8 ];
            size_t base = (size_t)(kk*64 + l)*8;
            ull2 pr;
            pr[0] = sys_ld64(hbuf + base);
            pr[1] = sys_ld64(hbuf + base + 4);
            short8 b = __builtin_bit_cast(short8, pr);
            acc = __builtin_amdgcn_mfma_f32_16x16x32_bf16(a, b, acc, 0, 0, 0);
        }
        float h0 = fast_tanh(acc[0]);
        float h1 = fast_tanh(acc[1]);
        float h2 = fast_tanh(acc[2]);
        float h3 = fast_tanh(acc[3]);

        int rloc = mt*16 + ((l >> 4) << 2);
        int bloc = nt*16 + (l & 15);
        int lnp  = (l & 15) | (((rloc >> 3) & 3) << 4);
        us4 hw = { f2bf(h0), f2bf(h1), f2bf(h2), f2bf(h3) };
        size_t widx = (((size_t)(gb*2 + nt)*32 + gr)*64 + lnp)*8 + (rloc & 7);
        sys_st64(&g_h[rb ^ 1][widx], __builtin_bit_cast(unsigned long long, hw));

        if (t == SEQ-1){
            f32x4 hf = {h0, h1, h2, h3};
            *(f32x4*)&g_hfinal[b0 + bloc][r0 + rloc] = hf;   // plain; kernel-end flush
        } else {
            wave_arrive(gb, gr, wv, l, t + 2);
        }
    }

    // ---- epilogue: race-free flag reset for graph replay
    __syncthreads();                          // all 4 waves past final wait
    if (tid == 0){
        __hip_atomic_fetch_add(&g_done[gb*64], 1u, __ATOMIC_ACQ_REL, __HIP_MEMORY_SCOPE_SYSTEM);
        if (gr == 0){
            int guard = 0;
            while (__hip_atomic_load(&g_done[gb*64], __ATOMIC_ACQUIRE, __HIP_MEMORY_SCOPE_SYSTEM) < GRN
                   && ++guard < (1 << 22)) { }
            for (int i = 0; i < 128; ++i)
                __hip_atomic_store(&g_flag[gb][i], 0, __ATOMIC_RELAXED, __HIP_MEMORY_SCOPE_SYSTEM);
            __hip_atomic_store(&g_done[gb*64], 0u, __ATOMIC_RELAXED, __HIP_MEMORY_SCOPE_SYSTEM);
        }
    }
}

// p = w_ph @ h_final + b_p ; out[b][c]
__global__ __launch_bounds__(TPB, 1) void proj_kernel(
    const float* __restrict__ w_ph, const float* __restrict__ b_p, float* __restrict__ out)
{
    const int b   = blockIdx.x;
    const int tid = threadIdx.x;
    const int l   = tid & 63;
    const int wv  = tid >> 6;
    __shared__ float red[4];
    f32x4 hv = *(const f32x4*)(&g_hfinal[b][0] + tid*4);
    for (int c = 0; c < NCLS; ++c){
        f32x4 wvv = *(const f32x4*)(w_ph + c*HD + tid*4);
        float s = hv[0]*wvv[0] + hv[1]*wvv[1] + hv[2]*wvv[2] + hv[3]*wvv[3];
        #pragma unroll
        for (int off = 32; off; off >>= 1) s += __shfl_down(s, off, 64);
        if (l == 0) red[wv] = s;
        __syncthreads();
        if (tid == 0) out[b*NCLS + c] = red[0] + red[1] + red[2] + red[3] + b_p[c];
        __syncthreads();
    }
}

extern "C" void kernel_launch(void* const* d_in, const int* in_sizes, int n_in,
                              void* d_out, int out_size, void* d_ws, size_t ws_size,
                              hipStream_t stream) {
    const float* x    = (const float*)d_in[0];
    const float* w_hx = (const float*)d_in[1];
    const float* w_hh = (const float*)d_in[2];
    const float* b_h  = (const float*)d_in[3];
    const float* w_ph = (const float*)d_in[4];
    const float* b_p  = (const float*)d_in[5];

    void* args[] = { (void*)&x, (void*)&w_hx, (void*)&w_hh, (void*)&b_h };
    hipError_t err = hipLaunchCooperativeKernel((void*)rnn_main, dim3(NWG), dim3(TPB),
                                                args, 0, stream);
    if (err != hipSuccess) {
        rnn_main<<<dim3(NWG), dim3(TPB), 0, stream>>>(x, w_hx, w_hh, b_h);
    }
    proj_kernel<<<dim3(BT), dim3(TPB), 0, stream>>>(w_ph, b_p, (float*)d_out);
}

// Round 5
// 3640.613 us; speedup vs baseline: 1.6717x; 1.6717x over previous
//
#include <hip/hip_runtime.h>

#define SEQ  512
#define IDIM 256
#define HD   1024
#define BT   256
#define NCLS 10

#define GRN 32   // row groups (32 rows of H each)
#define GBN 8    // batch groups (32 batch cols each)
#define NWG (GRN*GBN)
#define TPB 256

typedef __attribute__((ext_vector_type(8))) short short8;
typedef __attribute__((ext_vector_type(4))) float f32x4;
typedef __attribute__((ext_vector_type(4))) unsigned short us4;
typedef __attribute__((ext_vector_type(2))) unsigned long long ull2;

// h double buffer in MFMA-B fragment order (layout as R1-R3).
// ALL cross-WG data (h, flags) moves through the TCC via system-scope
// relaxed atomics (sc0+sc1) -- correct regardless of WG->XCD placement
// (R4's placement-dependent fast path is abandoned).
__device__ unsigned short g_h[2][GBN*2*32*64*8];
__device__ float g_hfinal[BT][HD];           // [b][k] fp32 final hidden state
__device__ int g_flag[GBN][64];              // per-WG arrival flags (32 used), 256B/group
__device__ unsigned int g_done[GBN*64];      // padded done counters

__device__ __forceinline__ unsigned short f2bf(float f){
    unsigned int u = __builtin_bit_cast(unsigned int, f);
    u += 0x7fffu + ((u >> 16) & 1u);         // round-to-nearest-even
    return (unsigned short)(u >> 16);
}

__device__ __forceinline__ float fast_tanh(float v){
    float e = __expf(2.0f * v);              // exact: tanh = 1 - 2/(e^2v+1)
    return 1.0f - 2.0f / (e + 1.0f);
}

__device__ __forceinline__ void sys_st64(unsigned short* p, unsigned long long v){
    __hip_atomic_store((unsigned long long*)p, v, __ATOMIC_RELAXED, __HIP_MEMORY_SCOPE_SYSTEM);
}
__device__ __forceinline__ unsigned long long sys_ld64(const unsigned short* p){
    return __hip_atomic_load((const unsigned long long*)p, __ATOMIC_RELAXED, __HIP_MEMORY_SCOPE_SYSTEM);
}

__global__ __launch_bounds__(TPB, 1) void rnn_main(
    const float* __restrict__ x, const float* __restrict__ w_hx,
    const float* __restrict__ w_hh, const float* __restrict__ b_h)
{
    __shared__ unsigned short sAB[2*40*64*8]; // 80 KB frag-order weights

    const int tid = threadIdx.x;
    const int wg  = blockIdx.x;
    const int gr  = wg >> 3;
    const int gb  = wg & 7;
    const int r0  = gr * 32;
    const int b0  = gb * 32;
    const int l   = tid & 63;
    const int wv  = tid >> 6;
    const int mt  = wv >> 1;
    const int nt  = wv & 1;

    // ---- W_hh rows [r0,r0+32) -> frag-order LDS, kk = 0..31
    for (int j = 0; j < 32; ++j){
        int idx = j*TPB + tid;
        int r = idx >> 8;
        int k = (idx & 255) << 2;
        f32x4 v = *(const f32x4*)(w_hh + (size_t)(r0 + r)*HD + k);
        int kk  = k >> 5;
        int ln  = (r & 15) | (((k >> 3) & 3) << 4);
        int mtw = r >> 4;
        us4 u = { f2bf(v[0]), f2bf(v[1]), f2bf(v[2]), f2bf(v[3]) };
        *(us4*)&sAB[ ((mtw*40 + kk)*64 + ln)*8 + (k & 7) ] = u;
    }
    // ---- w_hx rows -> frag-order LDS, kk = 32..39
    for (int j = 0; j < 8; ++j){
        int idx = j*TPB + tid;
        int r = idx >> 6;
        int k = (idx & 63) << 2;
        f32x4 v = *(const f32x4*)(w_hx + (size_t)(r0 + r)*IDIM + k);
        int kk  = 32 + (k >> 5);
        int ln  = (r & 15) | (((k >> 3) & 3) << 4);
        int mtw = r >> 4;
        us4 u = { f2bf(v[0]), f2bf(v[1]), f2bf(v[2]), f2bf(v[3]) };
        *(us4*)&sAB[ ((mtw*40 + kk)*64 + ln)*8 + (k & 7) ] = u;
    }
    // ---- zero our kk=gr slice of h buffer 0 (h_init = 0), TCC-direct
    if (tid < 128){
        int ntz = tid >> 6, lz = tid & 63;
        size_t base = (((size_t)(gb*2 + ntz)*32 + gr)*64 + lz)*8;
        sys_st64(&g_h[0][base],     0ull);
        sys_st64(&g_h[0][base + 4], 0ull);
    }
    const f32x4 bh = *(const f32x4*)(b_h + r0 + mt*16 + ((l >> 4) << 2));
    const float* xlane = x + (size_t)(b0 + nt*16 + (l & 15)) * (SEQ*IDIM) + ((l >> 4) << 3);
    const unsigned short* sA = &sAB[ (size_t)mt * 40 * 512 ];
    const size_t hblk = (size_t)(gb*2 + nt) * 32 * 512;

    // arrive: drain all waves' TCC stores (syncthreads emits vmcnt(0) for
    // every wave before s_barrier), then ONE flag store per WG.
    auto arrive = [&](int val){
        asm volatile("s_waitcnt vmcnt(0)" ::: "memory");
        __syncthreads();
        if (tid == 0)
            __hip_atomic_store(&g_flag[gb][gr], val, __ATOMIC_RELAXED, __HIP_MEMORY_SCOPE_SYSTEM);
    };
    // wait: only wave 0 polls (2 cache lines); others held at the barrier.
    auto wait_all = [&](int val){
        if (wv == 0){
            const int idx = l & 31;
            int guard = 0;
            for (;;){
                int f = __hip_atomic_load(&g_flag[gb][idx], __ATOMIC_RELAXED, __HIP_MEMORY_SCOPE_SYSTEM);
                if (__all(f >= val)) break;
                if (++guard > (1 << 20)) break;   // hang safety
            }
        }
        __syncthreads();   // full compiler+HW barrier: h loads can't hoist above
    };

    arrive(1);                                // weights staged + buf0 zeros published

    for (int t = 0; t < SEQ; ++t){
        const int rb = t & 1;
        f32x4 acc = bh;

        // ---- x-part first (independent of h): overlaps producer latency
        const float* xp = xlane + (size_t)t*IDIM;
        #pragma unroll
        for (int kk = 0; kk < 8; ++kk){
            f32x4 v0 = *(const f32x4*)(xp + kk*32);
            f32x4 v1 = *(const f32x4*)(xp + kk*32 + 4);
            short8 bx;
            bx[0] = (short)f2bf(v0[0]); bx[1] = (short)f2bf(v0[1]);
            bx[2] = (short)f2bf(v0[2]); bx[3] = (short)f2bf(v0[3]);
            bx[4] = (short)f2bf(v1[0]); bx[5] = (short)f2bf(v1[1]);
            bx[6] = (short)f2bf(v1[2]); bx[7] = (short)f2bf(v1[3]);
            short8 a = *(const short8*)&sA[ ((32 + kk)*64 + l)*8 ];
            acc = __builtin_amdgcn_mfma_f32_16x16x32_bf16(a, bx, acc, 0, 0, 0);
        }

        wait_all(t + 1);                      // h_t published by all 32 WGs of group

        // ---- recurrent part: K = 1024, h read TCC-direct
        const unsigned short* hbuf = &g_h[rb][hblk];
        #pragma unroll 8
        for (int kk = 0; kk < 32; ++kk){
            short8 a = *(const short8*)&sA[ (kk*64 + l)*8 ];
            size_t base = (size_t)(kk*64 + l)*8;
            ull2 pr;
            pr[0] = sys_ld64(hbuf + base);
            pr[1] = sys_ld64(hbuf + base + 4);
            acc = __builtin_amdgcn_mfma_f32_16x16x32_bf16(
                      a, __builtin_bit_cast(short8, pr), acc, 0, 0, 0);
        }

        float h0 = fast_tanh(acc[0]);
        float h1 = fast_tanh(acc[1]);
        float h2 = fast_tanh(acc[2]);
        float h3 = fast_tanh(acc[3]);

        int rloc = mt*16 + ((l >> 4) << 2);
        int bloc = nt*16 + (l & 15);
        int lnp  = (l & 15) | (((rloc >> 3) & 3) << 4);
        us4 hw = { f2bf(h0), f2bf(h1), f2bf(h2), f2bf(h3) };
        size_t widx = (((size_t)(gb*2 + nt)*32 + gr)*64 + lnp)*8 + (rloc & 7);
        sys_st64(&g_h[rb ^ 1][widx], __builtin_bit_cast(unsigned long long, hw));

        if (t == SEQ-1){
            f32x4 hf = {h0, h1, h2, h3};
            *(f32x4*)&g_hfinal[b0 + bloc][r0 + rloc] = hf;   // plain; kernel-end flush
        } else {
            arrive(t + 2);
        }
    }

    // ---- epilogue: race-free flag reset for graph replay
    __syncthreads();                          // all waves past final wait
    if (tid == 0){
        __hip_atomic_fetch_add(&g_done[gb*64], 1u, __ATOMIC_ACQ_REL, __HIP_MEMORY_SCOPE_SYSTEM);
        if (gr == 0){
            int guard = 0;
            while (__hip_atomic_load(&g_done[gb*64], __ATOMIC_ACQUIRE, __HIP_MEMORY_SCOPE_SYSTEM) < GRN
                   && ++guard < (1 << 22)) { }
            for (int i = 0; i < 64; ++i)
                __hip_atomic_store(&g_flag[gb][i], 0, __ATOMIC_RELAXED, __HIP_MEMORY_SCOPE_SYSTEM);
            __hip_atomic_store(&g_done[gb*64], 0u, __ATOMIC_RELAXED, __HIP_MEMORY_SCOPE_SYSTEM);
        }
    }
}

// p = w_ph @ h_final + b_p ; out[b][c]
__global__ __launch_bounds__(TPB, 1) void proj_kernel(
    const float* __restrict__ w_ph, const float* __restrict__ b_p, float* __restrict__ out)
{
    const int b   = blockIdx.x;
    const int tid = threadIdx.x;
    const int l   = tid & 63;
    const int wv  = tid >> 6;
    __shared__ float red[4];
    f32x4 hv = *(const f32x4*)(&g_hfinal[b][0] + tid*4);
    for (int c = 0; c < NCLS; ++c){
        f32x4 wvv = *(const f32x4*)(w_ph + c*HD + tid*4);
        float s = hv[0]*wvv[0] + hv[1]*wvv[1] + hv[2]*wvv[2] + hv[3]*wvv[3];
        #pragma unroll
        for (int off = 32; off; off >>= 1) s += __shfl_down(s, off, 64);
        if (l == 0) red[wv] = s;
        __syncthreads();
        if (tid == 0) out[b*NCLS + c] = red[0] + red[1] + red[2] + red[3] + b_p[c];
        __syncthreads();
    }
}

extern "C" void kernel_launch(void* const* d_in, const int* in_sizes, int n_in,
                              void* d_out, int out_size, void* d_ws, size_t ws_size,
                              hipStream_t stream) {
    const float* x    = (const float*)d_in[0];
    const float* w_hx = (const float*)d_in[1];
    const float* w_hh = (const float*)d_in[2];
    const float* b_h  = (const float*)d_in[3];
    const float* w_ph = (const float*)d_in[4];
    const float* b_p  = (const float*)d_in[5];

    void* args[] = { (void*)&x, (void*)&w_hx, (void*)&w_hh, (void*)&b_h };
    hipError_t err = hipLaunchCooperativeKernel((void*)rnn_main, dim3(NWG), dim3(TPB),
                                                args, 0, stream);
    if (err != hipSuccess) {
        rnn_main<<<dim3(NWG), dim3(TPB), 0, stream>>>(x, w_hx, w_hh, b_h);
    }
    proj_kernel<<<dim3(BT), dim3(TPB), 0, stream>>>(w_ph, b_p, (float*)d_out);
}